// Round 1
// baseline (124.115 us; speedup 1.0000x reference)
//
#include <hip/hip_runtime.h>
#include <hip/hip_bf16.h>

// LayerNorm(K=128) + Linear(128x128), fused. fp32 in/out, bf16 MFMA inside.
// M=524288 rows. Memory-bound: 512 MiB HBM traffic -> ~85us floor.

#define K_DIM 128
#define N_DIM 128
#define ROWS_PER_TILE 64
#define TILES_PER_BLOCK 4
#define LDS_STRIDE 136  // 128 + 8 bf16 pad: row stride 272B -> 2-way bank alias (free)

typedef __attribute__((ext_vector_type(8))) short bf16x8;
typedef __attribute__((ext_vector_type(4))) float f32x4;

__device__ __forceinline__ unsigned short f2bf(float f) {
    union { float f; unsigned int u; } v; v.f = f;
    unsigned int u = v.u;
    // round-to-nearest-even bf16 (inputs are normal floats)
    return (unsigned short)((u + 0x7fffu + ((u >> 16) & 1u)) >> 16);
}

__global__ __launch_bounds__(256, 2) void lnlin_kernel(
    const float* __restrict__ x, const float* __restrict__ lnw,
    const float* __restrict__ lnb, const float* __restrict__ B,
    float* __restrict__ out)
{
    __shared__ __align__(16) unsigned short sBT[N_DIM * LDS_STRIDE];       // [n][k] bf16
    __shared__ __align__(16) unsigned short sA[ROWS_PER_TILE * LDS_STRIDE]; // [m][k] bf16

    const int tid  = threadIdx.x;
    const int wave = tid >> 6;
    const int lane = tid & 63;
    const int h    = lane >> 5;   // half-wave
    const int s    = lane & 31;   // sub-lane within half-wave

    // --- stage B: global [K][N] fp32 -> LDS [N][K] bf16 (transposed, padded) ---
    {
        const int n0    = (tid & 31) * 4;
        const int kbase = tid >> 5;
        #pragma unroll
        for (int p = 0; p < 16; ++p) {
            const int k = kbase + p * 8;
            const float4 b4 = *(const float4*)(B + k * N_DIM + n0);
            sBT[(n0 + 0) * LDS_STRIDE + k] = f2bf(b4.x);
            sBT[(n0 + 1) * LDS_STRIDE + k] = f2bf(b4.y);
            sBT[(n0 + 2) * LDS_STRIDE + k] = f2bf(b4.z);
            sBT[(n0 + 3) * LDS_STRIDE + k] = f2bf(b4.w);
        }
    }

    // per-lane layernorm affine params for cols [s*4, s*4+4)
    const float4 wv = *(const float4*)(lnw + s * 4);
    const float4 bv = *(const float4*)(lnb + s * 4);

    __syncthreads();

    const int tile0 = blockIdx.x * TILES_PER_BLOCK;

    // prefetch x for first tile: half-wave per row, fully coalesced float4
    float4 v[8];
    {
        const float* xp = x + (size_t)tile0 * ROWS_PER_TILE * K_DIM;
        #pragma unroll
        for (int i = 0; i < 8; ++i) {
            const int lr = i * 8 + wave * 2 + h;
            v[i] = *(const float4*)(xp + lr * K_DIM + s * 4);
        }
    }

    for (int j = 0; j < TILES_PER_BLOCK; ++j) {
        const size_t rbase = (size_t)(tile0 + j) * ROWS_PER_TILE;

        // --- layernorm: stats via 32-lane shuffle reduce, normalize, bf16 -> sA ---
        #pragma unroll
        for (int i = 0; i < 8; ++i) {
            const int lr = i * 8 + wave * 2 + h;
            const float4 xv = v[i];
            float sum = (xv.x + xv.y) + (xv.z + xv.w);
            float sq  = xv.x * xv.x + xv.y * xv.y + xv.z * xv.z + xv.w * xv.w;
            #pragma unroll
            for (int mk = 1; mk < 32; mk <<= 1) {
                sum += __shfl_xor(sum, mk, 32);
                sq  += __shfl_xor(sq,  mk, 32);
            }
            const float mean = sum * 0.0078125f;                       // /128
            const float var  = fmaxf(sq * 0.0078125f - mean * mean, 0.0f);
            const float rstd = rsqrtf(var + 1e-5f);
            ushort4 pk;
            pk.x = f2bf((xv.x - mean) * rstd * wv.x + bv.x);
            pk.y = f2bf((xv.y - mean) * rstd * wv.y + bv.y);
            pk.z = f2bf((xv.z - mean) * rstd * wv.z + bv.z);
            pk.w = f2bf((xv.w - mean) * rstd * wv.w + bv.w);
            *(ushort4*)&sA[lr * LDS_STRIDE + s * 4] = pk;
        }
        __syncthreads();

        // prefetch next tile's x while MFMAs run (regs only, no LDS hazard)
        if (j + 1 < TILES_PER_BLOCK) {
            const float* xp = x + (rbase + ROWS_PER_TILE) * K_DIM;
            #pragma unroll
            for (int i = 0; i < 8; ++i) {
                const int lr = i * 8 + wave * 2 + h;
                v[i] = *(const float4*)(xp + lr * K_DIM + s * 4);
            }
        }

        // --- MFMA: wave w owns rows [w*16, w*16+16), all 8 N-tiles ---
        const int m  = lane & 15;
        const int kg = lane >> 4;
        f32x4 acc[8] = {};
        #pragma unroll
        for (int kk = 0; kk < 4; ++kk) {
            const bf16x8 af = *(const bf16x8*)&sA[(wave * 16 + m) * LDS_STRIDE + kk * 32 + kg * 8];
            #pragma unroll
            for (int t = 0; t < 8; ++t) {
                const bf16x8 bf = *(const bf16x8*)&sBT[(t * 16 + m) * LDS_STRIDE + kk * 32 + kg * 8];
                acc[t] = __builtin_amdgcn_mfma_f32_16x16x32_bf16(af, bf, acc[t], 0, 0, 0);
            }
        }

        // --- store: C/D layout col=lane&15, row=(lane>>4)*4+i ---
        float* op = out + (rbase + wave * 16 + kg * 4) * N_DIM;
        #pragma unroll
        for (int t = 0; t < 8; ++t) {
            #pragma unroll
            for (int i = 0; i < 4; ++i) {
                op[i * N_DIM + t * 16 + m] = acc[t][i];
            }
        }
        __syncthreads();  // all frag reads done before next tile overwrites sA
    }
}

extern "C" void kernel_launch(void* const* d_in, const int* in_sizes, int n_in,
                              void* d_out, int out_size, void* d_ws, size_t ws_size,
                              hipStream_t stream) {
    const float* x   = (const float*)d_in[0];
    const float* lnw = (const float*)d_in[1];
    const float* lnb = (const float*)d_in[2];
    const float* B   = (const float*)d_in[3];
    float* out = (float*)d_out;

    const int M = in_sizes[0] / K_DIM;                       // 524288
    const int grid = M / (ROWS_PER_TILE * TILES_PER_BLOCK);  // 2048

    hipLaunchKernelGGL(lnlin_kernel, dim3(grid), dim3(256), 0, stream,
                       x, lnw, lnb, B, out);
}